// Round 9
// baseline (108.764 us; speedup 1.0000x reference)
//
#include <hip/hip_runtime.h>
#include <math.h>
#include <stdint.h>

#define NS 200
#define THASH (1 << 19)
#define TMASK ((1u << 19) - 1u)
#define QCAP 192   // hard bound: <=64 leaders/level x 3 compacted levels

__device__ __forceinline__ float sigmoidf_(float v) {
    return 1.0f / (1.0f + __expf(-v));
}

// Kernel 1: one block (256 threads) per ray; lane s = sample s.
// Levels 0-2: run-leader cells compacted into an LDS queue (ballot prefix
// sums), drained with ALL 64 lanes active (8 cells x 8 corners per gather
// instruction) -> ~5 dense VMEM instrs replace 24 sparse masked ones.
// Level 3: masked loads + shfl broadcast. Level 4: direct per-lane loads.
__global__ __launch_bounds__(256) void k_label(
        const float* __restrict__ x,
        const float* __restrict__ tlab,
        const float* __restrict__ wlab, const float* __restrict__ blab,
        float* __restrict__ hits, float* __restrict__ labels,
        int* __restrict__ firsts)
{
    const uint32_t P2 = 2654435761u, P3 = 805459861u;
    const int b = blockIdx.x;
    const int tid = threadIdx.x;
    const int lane = tid & 63;
    const int wid = tid >> 6;

    __shared__ uint4 q[4][QCAP];          // per-wave queue: base, dx|lvl<<24, dy, dz
    __shared__ float vbuf[4][QCAP * 8];   // per-wave gathered corner values
    __shared__ float wmax[4];
    __shared__ int wmin[4];

    const float4 ray = *(const float4*)(x + 4 * (size_t)b);
    const int s_eff = tid < NS ? tid : NS - 1;
    const float t = (float)s_eff * (1.0f / 199.0f);
    const float px = ray.x * (1.0f - t) + ray.z * t;
    const float py = ray.y * (1.0f - t) + ray.w * t;
    const float pz = t;

    // finest level (res = 128); coarser levels derived by shifts
    const float xf4 = px * 128.0f, yf4 = py * 128.0f, zf4 = pz * 128.0f;
    const float fx4 = floorf(xf4), fy4 = floorf(yf4), fz4 = floorf(zf4);
    const uint32_t x4 = (uint32_t)(int)fx4;
    const uint32_t y4 = (uint32_t)(int)fy4;
    const uint32_t z4 = (uint32_t)(int)fz4;
    const uint32_t cell4 = x4 | (y4 << 10) | (z4 << 20);
    const uint32_t prev = __shfl_up(cell4, 1);
    const uint32_t diff = cell4 ^ prev;   // garbage at lane 0 (forced leader)

    const uint64_t mask_excl = (1ull << lane) - 1ull;
    const uint64_t mask_incl = mask_excl | (1ull << lane);

    // ---- leader flags / prefix slots for levels 0..2 (k = 4,3,2) ----
    bool led[3];
    int ldr[3], gslot[3];
    int S;
    {
        uint64_t bal0, bal1, bal2;
        #define LFLAG(L, K, BAL) { \
            const uint32_t fm = 0x3FFu & ~((1u << (K)) - 1u); \
            const uint32_t m_l = fm | (fm << 10) | (fm << 20); \
            led[L] = (lane == 0) || ((diff & m_l) != 0u); \
            BAL = __ballot(led[L]); \
            ldr[L] = 63 - __clzll(BAL & mask_incl); }
        LFLAG(0, 4, bal0)
        LFLAG(1, 3, bal1)
        LFLAG(2, 2, bal2)
        #undef LFLAG
        const int S0 = __popcll(bal0);
        const int S1 = __popcll(bal1);
        gslot[0] = __popcll(bal0 & mask_excl);
        gslot[1] = S0 + __popcll(bal1 & mask_excl);
        gslot[2] = S0 + S1 + __popcll(bal2 & mask_excl);
        S = S0 + S1 + __popcll(bal2);
    }

    // ---- enqueue leader cells ----
    #pragma unroll
    for (int l = 0; l < 3; ++l) {
        if (led[l]) {
            const int k = 4 - l;
            const uint32_t x0 = x4 >> k, y0 = y4 >> k, z0 = z4 >> k;
            const uint32_t hy0 = y0 * P2, hz0 = z0 * P3;
            const uint32_t base = x0 ^ hy0 ^ hz0;
            const uint32_t dxl = (x0 ^ (x0 + 1u)) | ((uint32_t)l << 24);
            const uint32_t dy = hy0 ^ (hy0 + P2);
            const uint32_t dz = hz0 ^ (hz0 + P3);
            q[wid][gslot[l]] = make_uint4(base, dxl, dy, dz);
        }
    }

    // ---- dense gather: 8 queue entries per iteration, corner = lane&7 ----
    {
        const int corner = lane & 7;
        const int sub = lane >> 3;
        const int nIt = (S + 7) >> 3;
        for (int it = 0; it < nIt; ++it) {
            const int e = it * 8 + sub;
            const bool valid = e < S;
            const uint4 ent = q[wid][valid ? e : 0];
            uint32_t idx = ent.x;
            if (corner & 4) idx ^= (ent.y & 0x00FFFFFFu);
            if (corner & 2) idx ^= ent.z;
            if (corner & 1) idx ^= ent.w;
            const uint32_t lvl = ent.y >> 24;
            const float v = tlab[((size_t)lvl << 19) + (idx & TMASK)];
            if (valid) vbuf[wid][e * 8 + corner] = v;
        }
    }

    // ---- consume levels 0..2 from vbuf ----
    float acc = blab[0];
    #pragma unroll
    for (int l = 0; l < 3; ++l) {
        const int k = 4 - l;
        const uint32_t x0 = x4 >> k, y0 = y4 >> k, z0 = z4 >> k;
        const float sc = 1.0f / (float)(1 << k);
        const float wx = fmaf(xf4, sc, -(float)x0);
        const float wy = fmaf(yf4, sc, -(float)y0);
        const float wz = fmaf(zf4, sc, -(float)z0);
        const int ms = __shfl(gslot[l], ldr[l]);
        const float4 lo = *(const float4*)&vbuf[wid][ms * 8];
        const float4 hi = *(const float4*)&vbuf[wid][ms * 8 + 4];
        const float c00 = fmaf(wz, lo.y - lo.x, lo.x);
        const float c01 = fmaf(wz, lo.w - lo.z, lo.z);
        const float c10 = fmaf(wz, hi.y - hi.x, hi.x);
        const float c11 = fmaf(wz, hi.w - hi.z, hi.z);
        const float c0 = fmaf(wy, c01 - c00, c00);
        const float c1 = fmaf(wy, c11 - c10, c10);
        const float cv = fmaf(wx, c1 - c0, c0);
        acc = fmaf(cv, wlab[l], acc);
    }

    // ---- level 3 (k=1): masked loads + shfl broadcast ----
    {
        const uint32_t fm = 0x3FFu & ~1u;
        const uint32_t m_l = fm | (fm << 10) | (fm << 20);
        const bool led3 = (lane == 0) || ((diff & m_l) != 0u);
        const uint64_t bal3 = __ballot(led3);
        const int ldr3 = 63 - __clzll(bal3 & mask_incl);

        const uint32_t x0 = x4 >> 1, y0 = y4 >> 1, z0 = z4 >> 1;
        const float wx = fmaf(xf4, 0.5f, -(float)x0);
        const float wy = fmaf(yf4, 0.5f, -(float)y0);
        const float wz = fmaf(zf4, 0.5f, -(float)z0);

        float v0 = 0.f, v1 = 0.f, v2 = 0.f, v3 = 0.f,
              v4v = 0.f, v5 = 0.f, v6 = 0.f, v7 = 0.f;
        if (led3) {
            const uint32_t hy0 = y0 * P2, hz0 = z0 * P3;
            const uint32_t base = x0 ^ hy0 ^ hz0;
            const uint32_t dx = x0 ^ (x0 + 1u);
            const uint32_t dy = hy0 ^ (hy0 + P2);
            const uint32_t dz = hz0 ^ (hz0 + P3);
            const float* __restrict__ tl = tlab + (size_t)3 * THASH;
            v0  = tl[ base                 & TMASK];
            v1  = tl[(base ^ dz)           & TMASK];
            v2  = tl[(base ^ dy)           & TMASK];
            v3  = tl[(base ^ dy ^ dz)      & TMASK];
            v4v = tl[(base ^ dx)           & TMASK];
            v5  = tl[(base ^ dx ^ dz)      & TMASK];
            v6  = tl[(base ^ dx ^ dy)      & TMASK];
            v7  = tl[(base ^ dx ^ dy ^ dz) & TMASK];
        }
        v0  = __shfl(v0, ldr3);  v1 = __shfl(v1, ldr3);
        v2  = __shfl(v2, ldr3);  v3 = __shfl(v3, ldr3);
        v4v = __shfl(v4v, ldr3); v5 = __shfl(v5, ldr3);
        v6  = __shfl(v6, ldr3);  v7 = __shfl(v7, ldr3);

        const float c00 = fmaf(wz, v1 - v0, v0);
        const float c01 = fmaf(wz, v3 - v2, v2);
        const float c10 = fmaf(wz, v5 - v4v, v4v);
        const float c11 = fmaf(wz, v7 - v6, v6);
        const float c0 = fmaf(wy, c01 - c00, c00);
        const float c1 = fmaf(wy, c11 - c10, c10);
        const float cv = fmaf(wx, c1 - c0, c0);
        acc = fmaf(cv, wlab[3], acc);
    }

    // ---- level 4 (res=128): direct per-lane loads ----
    {
        const float wx = xf4 - fx4, wy = yf4 - fy4, wz = zf4 - fz4;
        const uint32_t hy0 = y4 * P2, hz0 = z4 * P3;
        const uint32_t base = x4 ^ hy0 ^ hz0;
        const uint32_t dx = x4 ^ (x4 + 1u);
        const uint32_t dy = hy0 ^ (hy0 + P2);
        const uint32_t dz = hz0 ^ (hz0 + P3);
        const float* __restrict__ tl = tlab + (size_t)4 * THASH;
        const float v0  = tl[ base                 & TMASK];
        const float v1  = tl[(base ^ dz)           & TMASK];
        const float v2  = tl[(base ^ dy)           & TMASK];
        const float v3  = tl[(base ^ dy ^ dz)      & TMASK];
        const float v4v = tl[(base ^ dx)           & TMASK];
        const float v5  = tl[(base ^ dx ^ dz)      & TMASK];
        const float v6  = tl[(base ^ dx ^ dy)      & TMASK];
        const float v7  = tl[(base ^ dx ^ dy ^ dz) & TMASK];
        const float c00 = fmaf(wz, v1 - v0, v0);
        const float c01 = fmaf(wz, v3 - v2, v2);
        const float c10 = fmaf(wz, v5 - v4v, v4v);
        const float c11 = fmaf(wz, v7 - v6, v6);
        const float c0 = fmaf(wy, c01 - c00, c00);
        const float c1 = fmaf(wy, c11 - c10, c10);
        const float cv = fmaf(wx, c1 - c0, c0);
        acc = fmaf(cv, wlab[4], acc);
    }

    float lab = -1.0f;
    int cand = NS;
    if (tid < NS) {
        lab = sigmoidf_(acc);
        labels[(size_t)b * NS + tid] = lab;
        if (lab > 0.5f) cand = tid;
    }

    // ---- block reduce: max(label), min(first idx > 0.5) ----
    float m = lab;
    int c = cand;
    #pragma unroll
    for (int off = 32; off > 0; off >>= 1) {
        m = fmaxf(m, __shfl_xor(m, off));
        c = min(c, __shfl_xor(c, off));
    }
    if (lane == 0) { wmax[wid] = m; wmin[wid] = c; }
    __syncthreads();
    if (tid == 0) {
        float mm = fmaxf(fmaxf(wmax[0], wmax[1]), fmaxf(wmax[2], wmax[3]));
        int cc = min(min(wmin[0], wmin[1]), min(wmin[2], wmin[3]));
        hits[b] = mm;
        firsts[b] = (cc >= NS) ? 0 : cc;
    }
}

// Kernel 2: 512 blocks x 32 rays, 512 threads (8 waves).
// Phase A: 15 iters of one float4 gather/thread -> feat[32][120] in LDS.
// Phase B: each wave runs the MLP for 4 rays.
#define RPB 32
__global__ __launch_bounds__(512) void k_rgb(
        const float* __restrict__ x,
        const float* __restrict__ trgb,
        const int* __restrict__ firsts,
        const float* __restrict__ W1, const float* __restrict__ b1,
        const float* __restrict__ W2, const float* __restrict__ b2,
        const float* __restrict__ W3, const float* __restrict__ b3,
        const float* __restrict__ W4, const float* __restrict__ b4,
        float* __restrict__ rgb)
{
    const uint32_t P2 = 2654435761u, P3 = 805459861u;
    const int tid = threadIdx.x;
    const int lane = tid & 63;
    const int wid = tid >> 6;
    const int rayBase = blockIdx.x * RPB;

    __shared__ float feat[RPB][120];
    __shared__ float hs[RPB][64];

    const int corner = tid & 7;
    const int rp = tid >> 3;
    const int ray = rp >> 1;
    const int pairHalf = rp & 1;
    const int bi = (corner >> 2) & 1, bj = (corner >> 1) & 1, bk = corner & 1;

    const float4 rd = *(const float4*)(x + 4 * (size_t)(rayBase + ray));
    const int first = firsts[rayBase + ray];

    #pragma unroll
    for (int it = 0; it < 15; ++it) {
        const int pair = pairHalf * 15 + it;   // 0..29
        const int si = pair / 6;
        const int l = pair % 6;
        int scl = first + si - 2;
        scl = scl < 0 ? 0 : (scl > NS - 1 ? NS - 1 : scl);
        const float t = (float)scl * (1.0f / 199.0f);
        const float px = rd.x * (1.0f - t) + rd.z * t;
        const float py = rd.y * (1.0f - t) + rd.w * t;
        const float pz = t;
        const int res = 4 << l;
        const float xf = px * (float)res, yf = py * (float)res, zf = pz * (float)res;
        const float fx = floorf(xf), fy = floorf(yf), fz = floorf(zf);
        const float wx = xf - fx, wy = yf - fy, wz = zf - fz;
        const uint32_t x0 = (uint32_t)(int)fx, y0 = (uint32_t)(int)fy, z0 = (uint32_t)(int)fz;
        const uint32_t hx = x0 + (uint32_t)bi;
        const uint32_t hy = (y0 + (uint32_t)bj) * P2;
        const uint32_t hz = (z0 + (uint32_t)bk) * P3;
        const uint32_t idx = (hx ^ hy ^ hz) & TMASK;
        const float cw = (bi ? wx : 1.0f - wx) * (bj ? wy : 1.0f - wy) * (bk ? wz : 1.0f - wz);
        const float4 tv = *(const float4*)(trgb + (((size_t)l << 19) + idx) * 4);
        float vx = tv.x * cw, vy = tv.y * cw, vz = tv.z * cw, vw = tv.w * cw;
        #pragma unroll
        for (int mm = 1; mm < 8; mm <<= 1) {
            vx += __shfl_xor(vx, mm);
            vy += __shfl_xor(vy, mm);
            vz += __shfl_xor(vz, mm);
            vw += __shfl_xor(vw, mm);
        }
        if (corner == 0) {
            float* f = &feat[ray][si * 24 + l * 4];
            f[0] = vx; f[1] = vy; f[2] = vz; f[3] = vw;
        }
    }
    __syncthreads();

    const int r0 = wid * 4;

    float a0 = b1[lane], a1 = a0, a2 = a0, a3 = a0;
    #pragma unroll 6
    for (int i = 0; i < 120; i += 4) {
        const float4 f0 = *(const float4*)(&feat[r0 + 0][i]);
        const float4 f1 = *(const float4*)(&feat[r0 + 1][i]);
        const float4 f2 = *(const float4*)(&feat[r0 + 2][i]);
        const float4 f3 = *(const float4*)(&feat[r0 + 3][i]);
        #pragma unroll
        for (int j = 0; j < 4; ++j) {
            const float wv = W1[(i + j) * 64 + lane];
            a0 = fmaf(((const float*)&f0)[j], wv, a0);
            a1 = fmaf(((const float*)&f1)[j], wv, a1);
            a2 = fmaf(((const float*)&f2)[j], wv, a2);
            a3 = fmaf(((const float*)&f3)[j], wv, a3);
        }
    }
    hs[r0 + 0][lane] = fmaxf(a0, 0.f);
    hs[r0 + 1][lane] = fmaxf(a1, 0.f);
    hs[r0 + 2][lane] = fmaxf(a2, 0.f);
    hs[r0 + 3][lane] = fmaxf(a3, 0.f);
    __syncthreads();

    a0 = b2[lane]; a1 = a0; a2 = a0; a3 = a0;
    #pragma unroll 4
    for (int i = 0; i < 64; i += 4) {
        const float4 f0 = *(const float4*)(&hs[r0 + 0][i]);
        const float4 f1 = *(const float4*)(&hs[r0 + 1][i]);
        const float4 f2 = *(const float4*)(&hs[r0 + 2][i]);
        const float4 f3 = *(const float4*)(&hs[r0 + 3][i]);
        #pragma unroll
        for (int j = 0; j < 4; ++j) {
            const float wv = W2[(i + j) * 64 + lane];
            a0 = fmaf(((const float*)&f0)[j], wv, a0);
            a1 = fmaf(((const float*)&f1)[j], wv, a1);
            a2 = fmaf(((const float*)&f2)[j], wv, a2);
            a3 = fmaf(((const float*)&f3)[j], wv, a3);
        }
    }
    __syncthreads();
    hs[r0 + 0][lane] = fmaxf(a0, 0.f);
    hs[r0 + 1][lane] = fmaxf(a1, 0.f);
    hs[r0 + 2][lane] = fmaxf(a2, 0.f);
    hs[r0 + 3][lane] = fmaxf(a3, 0.f);
    __syncthreads();

    a0 = b3[lane]; a1 = a0; a2 = a0; a3 = a0;
    #pragma unroll 4
    for (int i = 0; i < 64; i += 4) {
        const float4 f0 = *(const float4*)(&hs[r0 + 0][i]);
        const float4 f1 = *(const float4*)(&hs[r0 + 1][i]);
        const float4 f2 = *(const float4*)(&hs[r0 + 2][i]);
        const float4 f3 = *(const float4*)(&hs[r0 + 3][i]);
        #pragma unroll
        for (int j = 0; j < 4; ++j) {
            const float wv = W3[(i + j) * 64 + lane];
            a0 = fmaf(((const float*)&f0)[j], wv, a0);
            a1 = fmaf(((const float*)&f1)[j], wv, a1);
            a2 = fmaf(((const float*)&f2)[j], wv, a2);
            a3 = fmaf(((const float*)&f3)[j], wv, a3);
        }
    }
    __syncthreads();
    hs[r0 + 0][lane] = fmaxf(a0, 0.f);
    hs[r0 + 1][lane] = fmaxf(a1, 0.f);
    hs[r0 + 2][lane] = fmaxf(a2, 0.f);
    hs[r0 + 3][lane] = fmaxf(a3, 0.f);
    __syncthreads();

    if (lane < 12) {
        const int r = lane / 3, ch = lane % 3;
        float acc = b4[ch];
        #pragma unroll 8
        for (int j = 0; j < 64; ++j)
            acc = fmaf(hs[r0 + r][j], W4[j * 3 + ch], acc);
        rgb[(size_t)(rayBase + r0 + r) * 3 + ch] = acc;
    }
}

extern "C" void kernel_launch(void* const* d_in, const int* in_sizes, int n_in,
                              void* d_out, int out_size, void* d_ws, size_t ws_size,
                              hipStream_t stream) {
    const float* x    = (const float*)d_in[0];
    const float* tlab = (const float*)d_in[1];
    const float* trgb = (const float*)d_in[2];
    const float* wlab = (const float*)d_in[3];
    const float* blab = (const float*)d_in[4];
    const float* W1   = (const float*)d_in[5];
    const float* b1   = (const float*)d_in[6];
    const float* W2   = (const float*)d_in[7];
    const float* b2   = (const float*)d_in[8];
    const float* W3   = (const float*)d_in[9];
    const float* b3   = (const float*)d_in[10];
    const float* W4   = (const float*)d_in[11];
    const float* b4   = (const float*)d_in[12];

    const int B = in_sizes[0] / 4;  // 16384

    float* hits   = (float*)d_out;                       // [B]
    float* labels = hits + B;                            // [B*NS]
    float* rgbout = labels + (size_t)B * NS;             // [B*3]
    int* firsts   = (int*)d_ws;                          // [B]

    k_label<<<B, 256, 0, stream>>>(x, tlab, wlab, blab, hits, labels, firsts);
    k_rgb<<<B / RPB, 512, 0, stream>>>(x, trgb, firsts,
                                       W1, b1, W2, b2, W3, b3, W4, b4, rgbout);
}

// Round 10
// 105.113 us; speedup vs baseline: 1.0347x; 1.0347x over previous
//
#include <hip/hip_runtime.h>
#include <math.h>
#include <stdint.h>

#define NS 200
#define THASH (1 << 19)
#define TMASK ((1u << 19) - 1u)

__device__ __forceinline__ float sigmoidf_(float v) {
    return 1.0f / (1.0f + __expf(-v));
}

// Kernel 1: one block (256 threads) per ray; lane s = sample s.
// Run-leader dedup + branchless corner pairing: dx==1 for even x0, so the
// two x-corners of each (y,z) pair share an aligned float2 -> 4 float2
// loads cover all 8 corners (even x0) or the 4 x0-corners (odd x0, 4 extra
// nested-masked scalar loads). Avg 6 line-requests/cell instead of 8, at
// the same 8 VMEM instruction slots.
__global__ __launch_bounds__(256) void k_label(
        const float* __restrict__ x,
        const float* __restrict__ tlab,
        const float* __restrict__ wlab, const float* __restrict__ blab,
        float* __restrict__ hits, float* __restrict__ labels,
        int* __restrict__ firsts)
{
    const uint32_t P2 = 2654435761u, P3 = 805459861u;
    const int b = blockIdx.x;
    const int tid = threadIdx.x;
    const int lane = tid & 63;
    const int wid = tid >> 6;
    const float4 ray = *(const float4*)(x + 4 * (size_t)b);

    const int s_eff = tid < NS ? tid : NS - 1;
    const float t = (float)s_eff * (1.0f / 199.0f);
    const float px = ray.x * (1.0f - t) + ray.z * t;
    const float py = ray.y * (1.0f - t) + ray.w * t;
    const float pz = t;

    // finest level (res = 128); coarser levels derived by shifts
    const float xf4 = px * 128.0f, yf4 = py * 128.0f, zf4 = pz * 128.0f;
    const float fx4 = floorf(xf4), fy4 = floorf(yf4), fz4 = floorf(zf4);
    const uint32_t x4 = (uint32_t)(int)fx4;
    const uint32_t y4 = (uint32_t)(int)fy4;
    const uint32_t z4 = (uint32_t)(int)fz4;
    const uint32_t cell4 = x4 | (y4 << 10) | (z4 << 20);
    const uint32_t prev = __shfl_up(cell4, 1);
    const uint32_t diff = cell4 ^ prev;   // garbage at lane 0 (forced leader)
    const uint64_t mask_incl = (~0ull >> (63 - lane));

    float acc = blab[0];

    #pragma unroll
    for (int l = 0; l < 5; ++l) {
        const int k = 4 - l;   // 4,3,2,1,0
        bool leader;
        int ldr = lane;
        if (l < 4) {
            const uint32_t fm = 0x3FFu & ~((1u << k) - 1u);
            const uint32_t m_l = fm | (fm << 10) | (fm << 20);
            leader = (lane == 0) || ((diff & m_l) != 0u);
            const uint64_t bal = __ballot(leader);
            ldr = 63 - __clzll(bal & mask_incl);
        } else {
            leader = true;
        }

        const uint32_t x0 = x4 >> k, y0 = y4 >> k, z0 = z4 >> k;
        const float sc = 1.0f / (float)(1 << k);     // exact 2^-k
        const float wx = fmaf(xf4, sc, -(float)x0);
        const float wy = fmaf(yf4, sc, -(float)y0);
        const float wz = fmaf(zf4, sc, -(float)z0);

        float v0 = 0.f, v1 = 0.f, v2 = 0.f, v3 = 0.f,
              v4v = 0.f, v5 = 0.f, v6 = 0.f, v7 = 0.f;
        if (leader) {
            const uint32_t hy0 = y0 * P2, hz0 = z0 * P3;
            const uint32_t base = x0 ^ hy0 ^ hz0;
            const uint32_t dy = hy0 ^ (hy0 + P2);
            const uint32_t dz = hz0 ^ (hz0 + P3);
            const float* __restrict__ tl = tlab + (size_t)l * THASH;
            // the 4 x0-corner indices
            const uint32_t i00 =  base            & TMASK;
            const uint32_t i01 = (base ^ dz)      & TMASK;
            const uint32_t i10 = (base ^ dy)      & TMASK;
            const uint32_t i11 = (base ^ dy ^ dz) & TMASK;
            // paired loads: each covers {i, i^1}
            const float2 p00 = *(const float2*)(tl + (i00 & ~1u));
            const float2 p01 = *(const float2*)(tl + (i01 & ~1u));
            const float2 p10 = *(const float2*)(tl + (i10 & ~1u));
            const float2 p11 = *(const float2*)(tl + (i11 & ~1u));
            // odd x0: x1-corners are NOT i^1 -> 4 extra masked scalar loads
            const bool odd = (x0 & 1u) != 0u;
            float e0 = 0.f, e1 = 0.f, e2 = 0.f, e3 = 0.f;
            if (odd) {
                const uint32_t dx = x0 ^ (x0 + 1u);
                e0 = tl[(i00 ^ dx) & TMASK];
                e1 = tl[(i01 ^ dx) & TMASK];
                e2 = tl[(i10 ^ dx) & TMASK];
                e3 = tl[(i11 ^ dx) & TMASK];
            }
            // unswizzle
            const float a00 = (i00 & 1u) ? p00.y : p00.x;
            const float o00 = (i00 & 1u) ? p00.x : p00.y;
            const float a01 = (i01 & 1u) ? p01.y : p01.x;
            const float o01 = (i01 & 1u) ? p01.x : p01.y;
            const float a10 = (i10 & 1u) ? p10.y : p10.x;
            const float o10 = (i10 & 1u) ? p10.x : p10.y;
            const float a11 = (i11 & 1u) ? p11.y : p11.x;
            const float o11 = (i11 & 1u) ? p11.x : p11.y;
            v0  = a00;  v4v = odd ? e0 : o00;
            v1  = a01;  v5  = odd ? e1 : o01;
            v2  = a10;  v6  = odd ? e2 : o10;
            v3  = a11;  v7  = odd ? e3 : o11;
        }
        if (l < 4) {
            v0  = __shfl(v0, ldr);  v1 = __shfl(v1, ldr);
            v2  = __shfl(v2, ldr);  v3 = __shfl(v3, ldr);
            v4v = __shfl(v4v, ldr); v5 = __shfl(v5, ldr);
            v6  = __shfl(v6, ldr);  v7 = __shfl(v7, ldr);
        }

        const float c00 = fmaf(wz, v1 - v0, v0);
        const float c01 = fmaf(wz, v3 - v2, v2);
        const float c10 = fmaf(wz, v5 - v4v, v4v);
        const float c11 = fmaf(wz, v7 - v6, v6);
        const float c0 = fmaf(wy, c01 - c00, c00);
        const float c1 = fmaf(wy, c11 - c10, c10);
        const float cv = fmaf(wx, c1 - c0, c0);
        acc = fmaf(cv, wlab[l], acc);
    }

    float lab = -1.0f;
    int cand = NS;
    if (tid < NS) {
        lab = sigmoidf_(acc);
        labels[(size_t)b * NS + tid] = lab;
        if (lab > 0.5f) cand = tid;
    }

    // ---- block reduce: max(label), min(first idx > 0.5) ----
    __shared__ float wmax[4];
    __shared__ int wmin[4];
    float m = lab;
    int c = cand;
    #pragma unroll
    for (int off = 32; off > 0; off >>= 1) {
        m = fmaxf(m, __shfl_xor(m, off));
        c = min(c, __shfl_xor(c, off));
    }
    if (lane == 0) { wmax[wid] = m; wmin[wid] = c; }
    __syncthreads();
    if (tid == 0) {
        float mm = fmaxf(fmaxf(wmax[0], wmax[1]), fmaxf(wmax[2], wmax[3]));
        int cc = min(min(wmin[0], wmin[1]), min(wmin[2], wmin[3]));
        hits[b] = mm;
        firsts[b] = (cc >= NS) ? 0 : cc;
    }
}

// Kernel 2: 512 blocks x 32 rays, 512 threads (8 waves).
// Phase A: 15 iters of one float4 gather/thread -> feat[32][120] in LDS.
// Phase B: each wave runs the MLP for 4 rays.
#define RPB 32
__global__ __launch_bounds__(512) void k_rgb(
        const float* __restrict__ x,
        const float* __restrict__ trgb,
        const int* __restrict__ firsts,
        const float* __restrict__ W1, const float* __restrict__ b1,
        const float* __restrict__ W2, const float* __restrict__ b2,
        const float* __restrict__ W3, const float* __restrict__ b3,
        const float* __restrict__ W4, const float* __restrict__ b4,
        float* __restrict__ rgb)
{
    const uint32_t P2 = 2654435761u, P3 = 805459861u;
    const int tid = threadIdx.x;
    const int lane = tid & 63;
    const int wid = tid >> 6;
    const int rayBase = blockIdx.x * RPB;

    __shared__ float feat[RPB][120];
    __shared__ float hs[RPB][64];

    const int corner = tid & 7;
    const int rp = tid >> 3;
    const int ray = rp >> 1;
    const int pairHalf = rp & 1;
    const int bi = (corner >> 2) & 1, bj = (corner >> 1) & 1, bk = corner & 1;

    const float4 rd = *(const float4*)(x + 4 * (size_t)(rayBase + ray));
    const int first = firsts[rayBase + ray];

    #pragma unroll
    for (int it = 0; it < 15; ++it) {
        const int pair = pairHalf * 15 + it;   // 0..29
        const int si = pair / 6;
        const int l = pair % 6;
        int scl = first + si - 2;
        scl = scl < 0 ? 0 : (scl > NS - 1 ? NS - 1 : scl);
        const float t = (float)scl * (1.0f / 199.0f);
        const float px = rd.x * (1.0f - t) + rd.z * t;
        const float py = rd.y * (1.0f - t) + rd.w * t;
        const float pz = t;
        const int res = 4 << l;
        const float xf = px * (float)res, yf = py * (float)res, zf = pz * (float)res;
        const float fx = floorf(xf), fy = floorf(yf), fz = floorf(zf);
        const float wx = xf - fx, wy = yf - fy, wz = zf - fz;
        const uint32_t x0 = (uint32_t)(int)fx, y0 = (uint32_t)(int)fy, z0 = (uint32_t)(int)fz;
        const uint32_t hx = x0 + (uint32_t)bi;
        const uint32_t hy = (y0 + (uint32_t)bj) * P2;
        const uint32_t hz = (z0 + (uint32_t)bk) * P3;
        const uint32_t idx = (hx ^ hy ^ hz) & TMASK;
        const float cw = (bi ? wx : 1.0f - wx) * (bj ? wy : 1.0f - wy) * (bk ? wz : 1.0f - wz);
        const float4 tv = *(const float4*)(trgb + (((size_t)l << 19) + idx) * 4);
        float vx = tv.x * cw, vy = tv.y * cw, vz = tv.z * cw, vw = tv.w * cw;
        #pragma unroll
        for (int mm = 1; mm < 8; mm <<= 1) {
            vx += __shfl_xor(vx, mm);
            vy += __shfl_xor(vy, mm);
            vz += __shfl_xor(vz, mm);
            vw += __shfl_xor(vw, mm);
        }
        if (corner == 0) {
            float* f = &feat[ray][si * 24 + l * 4];
            f[0] = vx; f[1] = vy; f[2] = vz; f[3] = vw;
        }
    }
    __syncthreads();

    const int r0 = wid * 4;

    float a0 = b1[lane], a1 = a0, a2 = a0, a3 = a0;
    #pragma unroll 6
    for (int i = 0; i < 120; i += 4) {
        const float4 f0 = *(const float4*)(&feat[r0 + 0][i]);
        const float4 f1 = *(const float4*)(&feat[r0 + 1][i]);
        const float4 f2 = *(const float4*)(&feat[r0 + 2][i]);
        const float4 f3 = *(const float4*)(&feat[r0 + 3][i]);
        #pragma unroll
        for (int j = 0; j < 4; ++j) {
            const float wv = W1[(i + j) * 64 + lane];
            a0 = fmaf(((const float*)&f0)[j], wv, a0);
            a1 = fmaf(((const float*)&f1)[j], wv, a1);
            a2 = fmaf(((const float*)&f2)[j], wv, a2);
            a3 = fmaf(((const float*)&f3)[j], wv, a3);
        }
    }
    hs[r0 + 0][lane] = fmaxf(a0, 0.f);
    hs[r0 + 1][lane] = fmaxf(a1, 0.f);
    hs[r0 + 2][lane] = fmaxf(a2, 0.f);
    hs[r0 + 3][lane] = fmaxf(a3, 0.f);
    __syncthreads();

    a0 = b2[lane]; a1 = a0; a2 = a0; a3 = a0;
    #pragma unroll 4
    for (int i = 0; i < 64; i += 4) {
        const float4 f0 = *(const float4*)(&hs[r0 + 0][i]);
        const float4 f1 = *(const float4*)(&hs[r0 + 1][i]);
        const float4 f2 = *(const float4*)(&hs[r0 + 2][i]);
        const float4 f3 = *(const float4*)(&hs[r0 + 3][i]);
        #pragma unroll
        for (int j = 0; j < 4; ++j) {
            const float wv = W2[(i + j) * 64 + lane];
            a0 = fmaf(((const float*)&f0)[j], wv, a0);
            a1 = fmaf(((const float*)&f1)[j], wv, a1);
            a2 = fmaf(((const float*)&f2)[j], wv, a2);
            a3 = fmaf(((const float*)&f3)[j], wv, a3);
        }
    }
    __syncthreads();
    hs[r0 + 0][lane] = fmaxf(a0, 0.f);
    hs[r0 + 1][lane] = fmaxf(a1, 0.f);
    hs[r0 + 2][lane] = fmaxf(a2, 0.f);
    hs[r0 + 3][lane] = fmaxf(a3, 0.f);
    __syncthreads();

    a0 = b3[lane]; a1 = a0; a2 = a0; a3 = a0;
    #pragma unroll 4
    for (int i = 0; i < 64; i += 4) {
        const float4 f0 = *(const float4*)(&hs[r0 + 0][i]);
        const float4 f1 = *(const float4*)(&hs[r0 + 1][i]);
        const float4 f2 = *(const float4*)(&hs[r0 + 2][i]);
        const float4 f3 = *(const float4*)(&hs[r0 + 3][i]);
        #pragma unroll
        for (int j = 0; j < 4; ++j) {
            const float wv = W3[(i + j) * 64 + lane];
            a0 = fmaf(((const float*)&f0)[j], wv, a0);
            a1 = fmaf(((const float*)&f1)[j], wv, a1);
            a2 = fmaf(((const float*)&f2)[j], wv, a2);
            a3 = fmaf(((const float*)&f3)[j], wv, a3);
        }
    }
    __syncthreads();
    hs[r0 + 0][lane] = fmaxf(a0, 0.f);
    hs[r0 + 1][lane] = fmaxf(a1, 0.f);
    hs[r0 + 2][lane] = fmaxf(a2, 0.f);
    hs[r0 + 3][lane] = fmaxf(a3, 0.f);
    __syncthreads();

    if (lane < 12) {
        const int r = lane / 3, ch = lane % 3;
        float acc = b4[ch];
        #pragma unroll 8
        for (int j = 0; j < 64; ++j)
            acc = fmaf(hs[r0 + r][j], W4[j * 3 + ch], acc);
        rgb[(size_t)(rayBase + r0 + r) * 3 + ch] = acc;
    }
}

extern "C" void kernel_launch(void* const* d_in, const int* in_sizes, int n_in,
                              void* d_out, int out_size, void* d_ws, size_t ws_size,
                              hipStream_t stream) {
    const float* x    = (const float*)d_in[0];
    const float* tlab = (const float*)d_in[1];
    const float* trgb = (const float*)d_in[2];
    const float* wlab = (const float*)d_in[3];
    const float* blab = (const float*)d_in[4];
    const float* W1   = (const float*)d_in[5];
    const float* b1   = (const float*)d_in[6];
    const float* W2   = (const float*)d_in[7];
    const float* b2   = (const float*)d_in[8];
    const float* W3   = (const float*)d_in[9];
    const float* b3   = (const float*)d_in[10];
    const float* W4   = (const float*)d_in[11];
    const float* b4   = (const float*)d_in[12];

    const int B = in_sizes[0] / 4;  // 16384

    float* hits   = (float*)d_out;                       // [B]
    float* labels = hits + B;                            // [B*NS]
    float* rgbout = labels + (size_t)B * NS;             // [B*3]
    int* firsts   = (int*)d_ws;                          // [B]

    k_label<<<B, 256, 0, stream>>>(x, tlab, wlab, blab, hits, labels, firsts);
    k_rgb<<<B / RPB, 512, 0, stream>>>(x, trgb, firsts,
                                       W1, b1, W2, b2, W3, b3, W4, b4, rgbout);
}